// Round 1
// baseline (190.049 us; speedup 1.0000x reference)
//
#include <hip/hip_runtime.h>

#define NN 100000
#define SS 50000
#define KK 32
#define CC 128
#define RPB 160          // rows per proj block; 625 * 160 = 100000
#define LDA 136          // LDS row stride in halfs (272 B = 17*16, b128-aligned)

typedef _Float16 f16x8 __attribute__((ext_vector_type(8)));
typedef _Float16 f16x4 __attribute__((ext_vector_type(4)));
typedef _Float16 f16x2 __attribute__((ext_vector_type(2)));
typedef float f32x4 __attribute__((ext_vector_type(4)));

// Workspace table T: per row i (512 B stride, 256 halfs):
//   T[i*256 +   0 .. 127] = fp16(word_vec[i])   (proj staging loop)
//   T[i*256 + 128 .. 255] = fp16(P[i])          (proj epilogue)

// ---------------------------------------------------------------------------
// Kernel 1 (fused convert+proj): P = leaky_relu(wv @ W^T + b) via
// mfma_f32_16x16x32_f16. 160 rows/block staged once into LDS (fp16, padded)
// with coalesced float4 loads; same loop publishes the fp16 wv copy to T.
// Epilogue change (this round): P-f16 is staged back into the sA rows that
// the sub-tile just finished reading (dead after the ds_reads; one barrier
// per sub fences the other waves), then bulk-copied to T at block end with
// fully-contiguous 256 B row stores. Replaces 8 scalar 2-B global stores per
// thread (32-B quarter-wave chunks -> partial-line L2 writes) with 128-B
// aligned full-line traffic.
// ---------------------------------------------------------------------------
__global__ __launch_bounds__(256) void proj_kernel(
    const float* __restrict__ wv,
    const float* __restrict__ W,
    const float* __restrict__ bias,
    _Float16* __restrict__ T,
    float* __restrict__ out)
{
    __shared__ _Float16 sA[RPB][LDA];

    const int t = threadIdx.x;
    const int base = blockIdx.x * RPB;

    // Stage A (160 x 128 fp32 -> fp16 LDS + T copy). 20 float4 per thread.
    #pragma unroll 4
    for (int i = 0; i < 20; i++) {
        const int idx = i * 256 + t;
        const int row = idx >> 5;
        const int c4 = (idx & 31) * 4;
        const float4 v = *(const float4*)(wv + (size_t)(base + row) * CC + c4);
        f16x4 h;
        h[0] = (_Float16)v.x; h[1] = (_Float16)v.y;
        h[2] = (_Float16)v.z; h[3] = (_Float16)v.w;
        *(f16x4*)&sA[row][c4] = h;
        *(f16x4*)(T + (size_t)(base + row) * 256 + c4) = h;
    }

    const int w = t >> 6;
    const int l = t & 63;
    const int q = l >> 4;      // quad 0..3
    const int c = l & 15;

    // B-frags: B[k][n] = W[n][k]; lane holds n = w*32+nch*16+c, k = kc*32+q*8+j
    f16x8 bf[2][4];
    float bo[2];
    #pragma unroll
    for (int nch = 0; nch < 2; nch++) {
        const int n = w * 32 + nch * 16 + c;
        bo[nch] = bias[n];
        const float* Wr = W + (size_t)n * CC;
        #pragma unroll
        for (int kc = 0; kc < 4; kc++) {
            const int k0 = kc * 32 + q * 8;
            const float4 w0 = *(const float4*)(Wr + k0);
            const float4 w1 = *(const float4*)(Wr + k0 + 4);
            f16x8 b;
            b[0] = (_Float16)w0.x; b[1] = (_Float16)w0.y;
            b[2] = (_Float16)w0.z; b[3] = (_Float16)w0.w;
            b[4] = (_Float16)w1.x; b[5] = (_Float16)w1.y;
            b[6] = (_Float16)w1.z; b[7] = (_Float16)w1.w;
            bf[nch][kc] = b;
        }
    }
    __syncthreads();

    #pragma unroll 2
    for (int sub = 0; sub < RPB / 16; sub++) {
        const int rl = sub * 16 + c;

        f16x8 af[4];
        #pragma unroll
        for (int kc = 0; kc < 4; kc++)
            af[kc] = *(const f16x8*)&sA[rl][kc * 32 + q * 8];

        // All waves have read this sub's 16 sA rows past this point; those
        // rows are then dead and safe to overwrite with P-f16 below.
        __syncthreads();

        f32x4 acc[2] = {{0.f, 0.f, 0.f, 0.f}, {0.f, 0.f, 0.f, 0.f}};
        #pragma unroll
        for (int kc = 0; kc < 4; kc++) {
            acc[0] = __builtin_amdgcn_mfma_f32_16x16x32_f16(af[kc], bf[0][kc], acc[0], 0, 0, 0);
            acc[1] = __builtin_amdgcn_mfma_f32_16x16x32_f16(af[kc], bf[1][kc], acc[1], 0, 0, 0);
        }

        // D layout: col = c (+tile offset), row = q*4 + reg.
        #pragma unroll
        for (int nch = 0; nch < 2; nch++) {
            const int col = w * 32 + nch * 16 + c;
            #pragma unroll
            for (int rr = 0; rr < 4; rr++) {
                const int rowl = sub * 16 + q * 4 + rr;
                float v = acc[nch][rr] + bo[nch];
                v = v > 0.f ? v : 0.2f * v;
                out[(size_t)(base + rowl) * CC + col] = v;
                sA[rowl][col] = (_Float16)v;   // stage P-f16 in dead sA rows
            }
        }
    }

    // Bulk-publish P-f16 to T second half: 256 B contiguous per row.
    __syncthreads();
    #pragma unroll 4
    for (int i = 0; i < 20; i++) {
        const int idx = i * 256 + t;
        const int row = idx >> 5;
        const int c4 = (idx & 31) * 4;
        *(f16x4*)(T + (size_t)(base + row) * 256 + 128 + c4) = *(const f16x4*)&sA[row][c4];
    }
}

// ---------------------------------------------------------------------------
// Kernel 2: one wave per s, lane = r*16+c. This round: agg-gather rows are
// redirected by MASK (not by p) -- mathematically identical (masked => p is
// exactly 0; exp-underflow => p==0 times finite = 0) with an explicit
// all-masked fallback (mask-only __any, keeps the uniform-1/32 case exact).
// The agg row then EQUALS the score row, so the vv address is the kh address
// + 256 B (imm offset, free), and all 17 gathers issue up-front before any
// dependent compute (sched_barrier pins the boundary). Per-wave MLP goes
// from ~4 to 17 outstanding 16-B gathers and the softmax->vv serialization
// (a full LLC round-trip) leaves the critical path. launch_bounds(256,4)
// admits the ~104 VGPRs this needs at 16 waves/CU.
// ---------------------------------------------------------------------------
__global__ __launch_bounds__(256, 4) void attn_kernel(
    const _Float16* __restrict__ T,
    const int* __restrict__ src_idx,
    const int* __restrict__ neighs,
    const int* __restrict__ mask,
    float* __restrict__ out)
{
    const int s = (blockIdx.x * 256 + threadIdx.x) >> 6;
    if (s >= SS) return;
    const int lane = threadIdx.x & 63;
    const int c = lane & 15;
    const int r = lane >> 4;

    int nbv[8];
    int mbits = 0;
    #pragma unroll
    for (int ch = 0; ch < 8; ch++) {
        nbv[ch] = neighs[s * KK + ch * 4 + r];
        mbits |= (mask[s * KK + ch * 4 + r] & 1) << ch;
    }
    const int src = src_idx[s];

    // all-masked s (never in this seed, but exactness is cheap): gather the
    // real neighbor rows so agg = mean(P[neighs]) matches the reference.
    const bool havem = (__any(mbits) != 0);

    const char* Tb = (const char*)T;
    const unsigned cb = (unsigned)c << 4;

    unsigned off[8];
    #pragma unroll
    for (int ch = 0; ch < 8; ch++) {
        const int row = (((mbits >> ch) & 1) || !havem) ? nbv[ch] : src;
        off[ch] = ((unsigned)row << 9) + cb;
    }

    // All gathers up-front: q + 8 score rows + 8 agg rows (same row, +256 B).
    const f16x8 qh = *(const f16x8*)(Tb + (((unsigned)src << 9) + cb));
    f16x8 kh[8];
    #pragma unroll
    for (int ch = 0; ch < 8; ch++)
        kh[ch] = *(const f16x8*)(Tb + off[ch]);
    f16x8 vv[8];
    #pragma unroll
    for (int ch = 0; ch < 8; ch++)
        vv[ch] = *(const f16x8*)(Tb + off[ch] + 256);
    __builtin_amdgcn_sched_barrier(0);

    float sc[8];
    #pragma unroll
    for (int ch = 0; ch < 8; ch++) {
        float d = 0.f;
        #pragma unroll
        for (int j = 0; j < 4; j++) {
            f16x2 qa; qa[0] = qh[2 * j];     qa[1] = qh[2 * j + 1];
            f16x2 ka; ka[0] = kh[ch][2 * j]; ka[1] = kh[ch][2 * j + 1];
            d = __builtin_amdgcn_fdot2(qa, ka, d, false);
        }
        d += __shfl_xor(d, 1);
        d += __shfl_xor(d, 2);
        d += __shfl_xor(d, 4);
        d += __shfl_xor(d, 8);
        sc[ch] = ((mbits >> ch) & 1) ? d * 5.0f : -1e6f;
    }

    // Softmax over 32 (8 regs x 4 r-groups). All-masked s -> uniform 1/32,
    // matching the reference exactly (rcp(32) is exact).
    float mx = sc[0];
    #pragma unroll
    for (int ch = 1; ch < 8; ch++) mx = fmaxf(mx, sc[ch]);
    mx = fmaxf(mx, __shfl_xor(mx, 16));
    mx = fmaxf(mx, __shfl_xor(mx, 32));

    float p[8];
    float sum = 0.f;
    #pragma unroll
    for (int ch = 0; ch < 8; ch++) {
        p[ch] = __expf(sc[ch] - mx);   // masked: exp(-1e6 - mx) == +0.0f
        sum += p[ch];
    }
    sum += __shfl_xor(sum, 16);
    sum += __shfl_xor(sum, 32);
    const float inv = __builtin_amdgcn_rcpf(sum);
    #pragma unroll
    for (int ch = 0; ch < 8; ch++) p[ch] *= inv;

    // Agg: vv already resident (masked rows redirected to src: p==0 exactly,
    // contributes 0; all-masked: p==1/32 against the true neighbor rows).
    float acc[8] = {0.f, 0.f, 0.f, 0.f, 0.f, 0.f, 0.f, 0.f};
    #pragma unroll
    for (int ch = 0; ch < 8; ch++) {
        #pragma unroll
        for (int j = 0; j < 8; j++)
            acc[j] += p[ch] * (float)vv[ch][j];
    }

    // Cross-group butterfly: sum the 4 r-group partials.
    #pragma unroll
    for (int j = 0; j < 8; j++) {
        acc[j] += __shfl_xor(acc[j], 16);
        acc[j] += __shfl_xor(acc[j], 32);
    }

    // lane (r,c) writes cols c*8 + r*2 + {0,1}: contiguous 512 B per wave.
    *((float2*)(out + (size_t)src * CC) + c * 4 + r) =
        make_float2(acc[r * 2], acc[r * 2 + 1]);
}

extern "C" void kernel_launch(void* const* d_in, const int* in_sizes, int n_in,
                              void* d_out, int out_size, void* d_ws, size_t ws_size,
                              hipStream_t stream)
{
    const float* wv   = (const float*)d_in[0];
    const int*   src  = (const int*)d_in[1];
    const int*   nei  = (const int*)d_in[2];
    const int*   msk  = (const int*)d_in[3];
    const float* W    = (const float*)d_in[4];
    const float* bias = (const float*)d_in[5];
    float* out = (float*)d_out;
    _Float16* T = (_Float16*)d_ws;   // 100000 * 512 B = 51.2 MB

    proj_kernel<<<NN / RPB, 256, 0, stream>>>(wv, W, bias, T, out);           // 625
    attn_kernel<<<(SS * 64) / 256, 256, 0, stream>>>(T, src, nei, msk, out);  // 12500
}